// Round 2
// 2003.384 us; speedup vs baseline: 1.5206x; 1.5206x over previous
//
#include <hip/hip_runtime.h>
#include <hip/hip_bf16.h>

#define T_STEPS 8
#define BATCH 32
#define RR 56
#define MROWS (BATCH*RR)        // 1792
#define H0 2048
#define H1 2048
#define H2 1024
#define D_IN 1024
#define F_OUT (RR*H2)           // 57344
#define MBIG (T_STEPS*MROWS)    // 14336

typedef short short8 __attribute__((ext_vector_type(8)));
typedef short s16x4 __attribute__((ext_vector_type(4)));
typedef float f32x4 __attribute__((ext_vector_type(4)));

// async global->LDS, 16B per lane; lds base must be wave-uniform (HW scatters lane i at base+16i)
__device__ __forceinline__ void stage16(const __hip_bfloat16* g, __hip_bfloat16* lds) {
    __builtin_amdgcn_global_load_lds(
        (const __attribute__((address_space(1))) unsigned int*)g,
        (__attribute__((address_space(3))) unsigned int*)lds, 16, 0, 0);
}

__device__ __forceinline__ float bf2f(short u) {
    __hip_bfloat16 h; __builtin_memcpy(&h, &u, 2); return __bfloat162float(h);
}

// ---------- Pool + 3-term bf16 split: x -> featP[3][14336][1024] ----------
__global__ __launch_bounds__(256) void pool_kernel(const float* __restrict__ x,
                                                   __hip_bfloat16* __restrict__ featP) {
    int tid = blockIdx.x * 256 + threadIdx.x;
    const int total = MBIG * 1024;
    if (tid >= total) return;
    int d    = tid & 1023;
    int rest = tid >> 10;
    int r  = rest % RR;
    int tb = rest / RR;
    int b  = tb & 31;
    int t  = tb >> 5;
    int c  = r / 14, tp = r % 14;
    int hp = d >> 5, wp = d & 31;
    int n0 = t * 29 + 2 * tp;
    const float* xp = x + (((size_t)(b * 4 + c) * 232 + n0) * 4096) + (hp * 2) * 64 + (wp * 2);
    float s = 0.f;
    #pragma unroll
    for (int kd = 0; kd < 3; ++kd) {
        const float* xq = xp + (size_t)kd * 4096;
        s += xq[0] + xq[1] + xq[64] + xq[65];
    }
    s *= (1.0f / 12.0f);
    const size_t PS = (size_t)MBIG * 1024;
    __hip_bfloat16 h = __float2bfloat16(s);
    float vh = __bfloat162float(h);
    __hip_bfloat16 m = __float2bfloat16(s - vh);
    float vm = __bfloat162float(m);
    __hip_bfloat16 l = __float2bfloat16(s - vh - vm);
    featP[tid] = h;
    featP[PS + tid] = m;
    featP[2 * PS + tid] = l;
}

// ---------- Weight transpose + split: W[K][N] fp32 -> Wt[3][N][K] bf16 ----------
__global__ __launch_bounds__(256) void wsplit(const float* __restrict__ W,
                                              __hip_bfloat16* __restrict__ Wt,
                                              int K, int N) {
    int idx = blockIdx.x * 256 + threadIdx.x;     // over N * (K/8)
    int kc8 = K >> 3;
    if (idx >= N * kc8) return;
    int n  = idx % N;          // lane-fast -> coalesced reads
    int kc = idx / N;
    short8 h, m, l;
    #pragma unroll
    for (int j = 0; j < 8; ++j) {
        float v = W[(size_t)(kc * 8 + j) * N + n];
        __hip_bfloat16 hb = __float2bfloat16(v);
        float vh = __bfloat162float(hb);
        __hip_bfloat16 mb = __float2bfloat16(v - vh);
        float vm = __bfloat162float(mb);
        __hip_bfloat16 lb = __float2bfloat16(v - vh - vm);
        unsigned short hh, mm2, ll;
        __builtin_memcpy(&hh, &hb, 2); __builtin_memcpy(&mm2, &mb, 2); __builtin_memcpy(&ll, &lb, 2);
        h[j] = (short)hh; m[j] = (short)mm2; l[j] = (short)ll;
    }
    const size_t PS = (size_t)N * K;
    short8* o0 = (short8*)(Wt + (size_t)n * K + kc * 8);
    short8* o1 = (short8*)(Wt + PS + (size_t)n * K + kc * 8);
    short8* o2 = (short8*)(Wt + 2 * PS + (size_t)n * K + kc * 8);
    *o0 = h; *o1 = m; *o2 = l;
}

// ---------- Plane-fused bf16 MFMA GEMM ----------
// C[z][M][N] = sum over masked (pa,pb) of A_pa[M][kslice_z] @ B_pb[N][kslice_z]^T-stored
// DBUF=0: m97 schedule (stage -> vmcnt0 -> barrier -> compute -> barrier)   [fc_in path]
// DBUF=1: 2-phase double-buffer (issue next stage, compute current, 1 barrier/step) + split-K
template<int BM, int BN, int PA, int PB, unsigned PMASK, int DBUF>
__global__ __launch_bounds__(256) void gemm_planes(
    const __hip_bfloat16* __restrict__ A, long aPS,
    const __hip_bfloat16* __restrict__ B, long bPS,
    int M, int N, int K, int kSlice,
    float* __restrict__ Cout)
{
    constexpr int BK = 32;
    constexpr int MT_M = BM / 32;
    constexpr int MT_N = BN / 32;
    constexpr int ASZ = PA * BM * BK;
    constexpr int BSZ = PB * BN * BK;
    constexpr int NBUF = DBUF ? 2 : 1;
    __shared__ __align__(16) __hip_bfloat16 As[NBUF * ASZ];
    __shared__ __align__(16) __hip_bfloat16 Bs[NBUF * BSZ];
    const int tid  = threadIdx.x;
    const int lane = tid & 63, wid = tid >> 6;
    const int lr = lane & 15, lg = lane >> 4;
    const int row0 = blockIdx.y * BM, col0 = blockIdx.x * BN;
    const int wm0 = (wid >> 1) * (BM / 2), wn0 = (wid & 1) * (BN / 2);
    const int grow = lane >> 2;        // row within a 16-row staging chunk
    const int gcol = (lane & 3) * 8;   // bf16 element offset within row
    const int kBeg = blockIdx.z * kSlice;
    const int kEnd = kBeg + kSlice;
    float* __restrict__ Cz = Cout + (size_t)blockIdx.z * ((size_t)M * N);

    f32x4 acc[MT_M][MT_N];
    #pragma unroll
    for (int i = 0; i < MT_M; ++i)
        #pragma unroll
        for (int j = 0; j < MT_N; ++j)
            acc[i][j] = (f32x4){0.f, 0.f, 0.f, 0.f};

    constexpr int ACALLS = PA * BM / 16;   // 16 rows (1KB) per wave-call
    constexpr int BCALLS = PB * BN / 16;

    auto stageAll = [&](int kk, int bsel) {
        for (int j = wid; j < ACALLS; j += 4) {
            int pa = j / (BM / 16), sub = j % (BM / 16);
            const __hip_bfloat16* g = A + (long)pa * aPS
                + (long)(row0 + sub * 16 + grow) * K + kk + gcol;
            stage16(g, &As[bsel * ASZ + (pa * BM + sub * 16) * BK]);
        }
        for (int j = wid; j < BCALLS; j += 4) {
            int pb = j / (BN / 16), sub = j % (BN / 16);
            const __hip_bfloat16* g = B + (long)pb * bPS
                + (long)(col0 + sub * 16 + grow) * K + kk + gcol;
            stage16(g, &Bs[bsel * BSZ + (pb * BN + sub * 16) * BK]);
        }
    };

    int buf = 0;
    if constexpr (DBUF) {
        stageAll(kBeg, 0);
        asm volatile("s_waitcnt vmcnt(0)" ::: "memory");
        __syncthreads();
    }

    for (int k0 = kBeg; k0 < kEnd; k0 += BK) {
        if constexpr (DBUF) {
            if (k0 + BK < kEnd) stageAll(k0 + BK, buf ^ 1);   // issue-early, no wait
        } else {
            stageAll(k0, 0);
            asm volatile("s_waitcnt vmcnt(0)" ::: "memory");
            __syncthreads();
        }

        const __hip_bfloat16* Ab = &As[buf * ASZ];
        const __hip_bfloat16* Bb = &Bs[buf * BSZ];
        short8 af[PA][MT_M], bf[PB][MT_N];
        #pragma unroll
        for (int pa = 0; pa < PA; ++pa)
            #pragma unroll
            for (int i = 0; i < MT_M; ++i)
                af[pa][i] = *(const short8*)&Ab[(pa * BM + wm0 + i * 16 + lr) * BK + lg * 8];
        #pragma unroll
        for (int pb = 0; pb < PB; ++pb)
            #pragma unroll
            for (int j = 0; j < MT_N; ++j)
                bf[pb][j] = *(const short8*)&Bb[(pb * BN + wn0 + j * 16 + lr) * BK + lg * 8];

        #pragma unroll
        for (int pa = 0; pa < PA; ++pa)
            #pragma unroll
            for (int pb = 0; pb < PB; ++pb)
                if ((PMASK >> (pa * PB + pb)) & 1u) {
                    #pragma unroll
                    for (int i = 0; i < MT_M; ++i)
                        #pragma unroll
                        for (int j = 0; j < MT_N; ++j)
                            acc[i][j] = __builtin_amdgcn_mfma_f32_16x16x32_bf16(
                                af[pa][i], bf[pb][j], acc[i][j], 0, 0, 0);
                }
        // single barrier per k-step in DBUF mode: drain the in-flight stage of buf^1,
        // and guarantee all waves finished reading buf before it is overwritten.
        asm volatile("s_waitcnt vmcnt(0)" ::: "memory");
        __syncthreads();
        if constexpr (DBUF) buf ^= 1;
    }

    #pragma unroll
    for (int i = 0; i < MT_M; ++i) {
        #pragma unroll
        for (int j = 0; j < MT_N; ++j) {
            #pragma unroll
            for (int r = 0; r < 4; ++r) {
                int m = row0 + wm0 + i * 16 + lg * 4 + r;  // D: row=(lane>>4)*4+reg
                int n = col0 + wn0 + j * 16 + lr;          // D: col=lane&15
                Cz[(long)m * N + n] = acc[i][j][r];
            }
        }
    }
}

// ---------- Vectorized split-K reduce + bias + LIF ----------
// cur = sum_s parts[s*stride + i] + bias; mem' = beta*mem + cur - (mem>thr)*thr; spk = (mem'-thr>0)
template<int SK>
__global__ __launch_bounds__(256) void lif_vec(
    const float* __restrict__ parts, long stride4,   // stride between split planes, in float4 units
    const float* __restrict__ bias, int nMask4,      // (N/4)-1, N power of 2
    float* __restrict__ mem, __hip_bfloat16* __restrict__ spk,
    const float* __restrict__ betas, int bi,
    const float* __restrict__ thrs, int ti, int NN4)
{
    int i = blockIdx.x * 256 + threadIdx.x;
    if (i >= NN4) return;
    const float4* pb = (const float4*)parts;
    float4 cur = ((const float4*)bias)[i & nMask4];
    #pragma unroll
    for (int s = 0; s < SK; ++s) {
        float4 p = pb[(long)s * stride4 + i];
        cur.x += p.x; cur.y += p.y; cur.z += p.z; cur.w += p.w;
    }
    float beta = fminf(fmaxf(betas[bi], 0.f), 1.f);
    float thr = thrs[ti];
    float4 mo = ((const float4*)mem)[i];
    float4 mn;
    mn.x = beta * mo.x + cur.x - ((mo.x > thr) ? thr : 0.f);
    mn.y = beta * mo.y + cur.y - ((mo.y > thr) ? thr : 0.f);
    mn.z = beta * mo.z + cur.z - ((mo.z > thr) ? thr : 0.f);
    mn.w = beta * mo.w + cur.w - ((mo.w > thr) ? thr : 0.f);
    ((float4*)mem)[i] = mn;
    s16x4 sv;
    sv[0] = (mn.x - thr > 0.f) ? (short)0x3F80 : (short)0;   // bf16 1.0 / 0.0
    sv[1] = (mn.y - thr > 0.f) ? (short)0x3F80 : (short)0;
    sv[2] = (mn.z - thr > 0.f) ? (short)0x3F80 : (short)0;
    sv[3] = (mn.w - thr > 0.f) ? (short)0x3F80 : (short)0;
    ((s16x4*)spk)[i] = sv;
}

// ---------- Readout stage 1: per-(batch, chunk) partial dot, 8 chunks ----------
__global__ __launch_bounds__(256) void out_part(
    const __hip_bfloat16* __restrict__ spk2, const float* __restrict__ W_out,
    double* __restrict__ pout)
{
    const int b = blockIdx.y, chunk = blockIdx.x, tid = threadIdx.x;
    const int CH = F_OUT / 8;                       // 7168
    const __hip_bfloat16* s = spk2 + (size_t)b * F_OUT + (size_t)chunk * CH;
    const float* W = W_out + (size_t)chunk * CH * 4;
    double a0 = 0, a1 = 0, a2 = 0, a3 = 0;
    #pragma unroll
    for (int it = 0; it < 7; ++it) {
        int i = (it * 256 + tid) * 4;
        s16x4 sv = *(const s16x4*)(s + i);
        #pragma unroll
        for (int j = 0; j < 4; ++j) {
            float f = bf2f(sv[j]);
            const float4 w = *(const float4*)(W + (size_t)(i + j) * 4);
            a0 += (double)(f * w.x);
            a1 += (double)(f * w.y);
            a2 += (double)(f * w.z);
            a3 += (double)(f * w.w);
        }
    }
    __shared__ double red[256][4];
    red[tid][0] = a0; red[tid][1] = a1; red[tid][2] = a2; red[tid][3] = a3;
    __syncthreads();
    for (int s2 = 128; s2 > 0; s2 >>= 1) {
        if (tid < s2) {
            red[tid][0] += red[tid + s2][0];
            red[tid][1] += red[tid + s2][1];
            red[tid][2] += red[tid + s2][2];
            red[tid][3] += red[tid + s2][3];
        }
        __syncthreads();
    }
    if (tid < 4) pout[((size_t)b * 8 + chunk) * 4 + tid] = red[0][tid];
}

// ---------- Readout stage 2: reduce 8 chunks + output LIF ----------
__global__ __launch_bounds__(128) void out_fin(
    const double* __restrict__ pout, const float* __restrict__ b_out,
    float* __restrict__ m_out, float* __restrict__ out,
    const float* __restrict__ betas, int t)
{
    const int tid = threadIdx.x;          // 128 = 32 batches x 4 classes
    const int b = tid >> 2, c = tid & 3;
    double s = 0;
    #pragma unroll
    for (int k = 0; k < 8; ++k) s += pout[((size_t)b * 8 + k) * 4 + c];
    float beta = fminf(fmaxf(betas[3], 0.f), 1.f);
    float cur = (float)s + b_out[c];
    float mold = m_out[b * 4 + c];
    float reset = (mold > 1.0f) ? 1.0f : 0.0f;
    float mnew = beta * mold + cur - reset;
    m_out[b * 4 + c] = mnew;
    out[((size_t)t * BATCH + b) * 4 + c] = (mnew - 1.0f > 0.0f) ? 1.0f : 0.0f;
}

extern "C" void kernel_launch(void* const* d_in, const int* in_sizes, int n_in,
                              void* d_out, int out_size, void* d_ws, size_t ws_size,
                              hipStream_t stream) {
    const float* x     = (const float*)d_in[0];
    const float* W_in  = (const float*)d_in[1];
    const float* b_in  = (const float*)d_in[2];
    const float* W_h1  = (const float*)d_in[3];
    const float* b_h1  = (const float*)d_in[4];
    const float* W_h2  = (const float*)d_in[5];
    const float* b_h2  = (const float*)d_in[6];
    const float* W_out = (const float*)d_in[7];
    const float* b_out = (const float*)d_in[8];
    const float* betas = (const float*)d_in[9];
    const float* thrs  = (const float*)d_in[10];
    float* out = (float*)d_out;

    char* ws = (char*)d_ws;
    size_t off = 0;
    float* m_in  = (float*)(ws + off); off += (size_t)MROWS * H0 * 4;
    float* m_h1  = (float*)(ws + off); off += (size_t)MROWS * H1 * 4;
    float* m_h2  = (float*)(ws + off); off += (size_t)MROWS * H2 * 4;
    float* m_out = (float*)(ws + off); off += 512;
    size_t zero_bytes = off;                                   // 36,700,672
    __hip_bfloat16* WtIn = (__hip_bfloat16*)(ws + off); off += (size_t)3 * H0 * D_IN * 2;
    __hip_bfloat16* WtH1 = (__hip_bfloat16*)(ws + off); off += (size_t)3 * H1 * H0 * 2;
    __hip_bfloat16* WtH2 = (__hip_bfloat16*)(ws + off); off += (size_t)3 * H2 * H1 * 2;
    __hip_bfloat16* featP = (__hip_bfloat16*)(ws + off); off += (size_t)3 * MBIG * D_IN * 2;
    float* curAll = (float*)(ws + off); off += (size_t)MBIG * H0 * 4;
    __hip_bfloat16* spk_in = (__hip_bfloat16*)(ws + off); off += (size_t)MROWS * H0 * 2;
    __hip_bfloat16* spk1   = (__hip_bfloat16*)(ws + off); off += (size_t)MROWS * H1 * 2;
    __hip_bfloat16* spk2   = (__hip_bfloat16*)(ws + off); off += (size_t)MROWS * H2 * 2;

    // featP (88 MB) is dead after the fc_in GEMM -> reuse for split-K partials (58.7 MB)
    // and the readout partials (8 KB at +64 MiB).
    float*  parts = (float*)featP;
    double* pout  = (double*)((char*)featP + (64u << 20));

    hipMemsetAsync(d_ws, 0, zero_bytes, stream);

    wsplit<<<(H0 * (D_IN / 8) + 255) / 256, 256, 0, stream>>>(W_in, WtIn, D_IN, H0);
    wsplit<<<(H1 * (H0 / 8) + 255) / 256, 256, 0, stream>>>(W_h1, WtH1, H0, H1);
    wsplit<<<(H2 * (H1 / 8) + 255) / 256, 256, 0, stream>>>(W_h2, WtH2, H1, H2);

    pool_kernel<<<(MBIG * D_IN + 255) / 256, 256, 0, stream>>>(x, featP);

    // fc_in: 6 split products (hh,hm,mh,hl,mm,lh) fused in one K-sweep; unchanged m97 path
    gemm_planes<64, 128, 3, 3, 0x5Fu, 0><<<dim3(H0 / 128, MBIG / 64, 1), 256, 0, stream>>>(
        featP, (long)MBIG * D_IN, WtIn, (long)H0 * D_IN,
        MBIG, H0, D_IN, D_IN, curAll);

    const int NN1_4 = MROWS * H1 / 4;   // 917504
    const int NN2_4 = MROWS * H2 / 4;   // 458752

    for (int t = 0; t < T_STEPS; ++t) {
        // LIF0 on precomputed fc_in currents
        lif_vec<1><<<(MROWS * H0 / 4 + 255) / 256, 256, 0, stream>>>(
            curAll + (size_t)t * MROWS * H0, 0, b_in, H0 / 4 - 1,
            m_in, spk_in, betas, 0, thrs, 0, MROWS * H0 / 4);
        // h1: 128x64 tile, split-K=4, double-buffered 2-phase
        gemm_planes<128, 64, 1, 3, 0x7u, 1><<<dim3(H1 / 64, MROWS / 128, 4), 256, 0, stream>>>(
            spk_in, 0L, WtH1, (long)H1 * H0,
            MROWS, H1, H0, H0 / 4, parts);
        lif_vec<4><<<(NN1_4 + 255) / 256, 256, 0, stream>>>(
            parts, NN1_4, b_h1, H1 / 4 - 1,
            m_h1, spk1, betas, 1, thrs, 1, NN1_4);
        // h2: same structure
        gemm_planes<128, 64, 1, 3, 0x7u, 1><<<dim3(H2 / 64, MROWS / 128, 4), 256, 0, stream>>>(
            spk1, 0L, WtH2, (long)H2 * H1,
            MROWS, H2, H1, H1 / 4, parts);
        lif_vec<4><<<(NN2_4 + 255) / 256, 256, 0, stream>>>(
            parts, NN2_4, b_h2, H2 / 4 - 1,
            m_h2, spk2, betas, 2, thrs, 2, NN2_4);
        // readout: 256-block partial stage + 1-block LIF finisher
        out_part<<<dim3(8, BATCH), 256, 0, stream>>>(spk2, W_out, pout);
        out_fin<<<1, 128, 0, stream>>>(pout, b_out, m_out, out, betas, t);
    }
    (void)in_sizes; (void)n_in; (void)out_size; (void)ws_size;
}

// Round 3
// 1994.716 us; speedup vs baseline: 1.5272x; 1.0043x over previous
//
#include <hip/hip_runtime.h>
#include <hip/hip_bf16.h>

#define T_STEPS 8
#define BATCH 32
#define RR 56
#define MROWS (BATCH*RR)        // 1792
#define H0 2048
#define H1 2048
#define H2 1024
#define D_IN 1024
#define F_OUT (RR*H2)           // 57344
#define MBIG (T_STEPS*MROWS)    // 14336

typedef short short8 __attribute__((ext_vector_type(8)));
typedef short s16x4 __attribute__((ext_vector_type(4)));
typedef float f32x4 __attribute__((ext_vector_type(4)));

// async global->LDS, 16B per lane; lds base must be wave-uniform (HW scatters lane i at base+16i)
__device__ __forceinline__ void stage16(const __hip_bfloat16* g, __hip_bfloat16* lds) {
    __builtin_amdgcn_global_load_lds(
        (const __attribute__((address_space(1))) unsigned int*)g,
        (__attribute__((address_space(3))) unsigned int*)lds, 16, 0, 0);
}

__device__ __forceinline__ float bf2f(short u) {
    __hip_bfloat16 h; __builtin_memcpy(&h, &u, 2); return __bfloat162float(h);
}

// ---------- Pool + 3-term bf16 split: x -> featP[3][14336][1024] ----------
__global__ __launch_bounds__(256) void pool_kernel(const float* __restrict__ x,
                                                   __hip_bfloat16* __restrict__ featP) {
    int tid = blockIdx.x * 256 + threadIdx.x;
    const int total = MBIG * 1024;
    if (tid >= total) return;
    int d    = tid & 1023;
    int rest = tid >> 10;
    int r  = rest % RR;
    int tb = rest / RR;
    int b  = tb & 31;
    int t  = tb >> 5;
    int c  = r / 14, tp = r % 14;
    int hp = d >> 5, wp = d & 31;
    int n0 = t * 29 + 2 * tp;
    const float* xp = x + (((size_t)(b * 4 + c) * 232 + n0) * 4096) + (hp * 2) * 64 + (wp * 2);
    float s = 0.f;
    #pragma unroll
    for (int kd = 0; kd < 3; ++kd) {
        const float* xq = xp + (size_t)kd * 4096;
        s += xq[0] + xq[1] + xq[64] + xq[65];
    }
    s *= (1.0f / 12.0f);
    const size_t PS = (size_t)MBIG * 1024;
    __hip_bfloat16 h = __float2bfloat16(s);
    float vh = __bfloat162float(h);
    __hip_bfloat16 m = __float2bfloat16(s - vh);
    float vm = __bfloat162float(m);
    __hip_bfloat16 l = __float2bfloat16(s - vh - vm);
    featP[tid] = h;
    featP[PS + tid] = m;
    featP[2 * PS + tid] = l;
}

// ---------- Weight transpose + split: W[K][N] fp32 -> Wt[3][N][K] bf16 ----------
__global__ __launch_bounds__(256) void wsplit(const float* __restrict__ W,
                                              __hip_bfloat16* __restrict__ Wt,
                                              int K, int N) {
    int idx = blockIdx.x * 256 + threadIdx.x;     // over N * (K/8)
    int kc8 = K >> 3;
    if (idx >= N * kc8) return;
    int n  = idx % N;          // lane-fast -> coalesced reads
    int kc = idx / N;
    short8 h, m, l;
    #pragma unroll
    for (int j = 0; j < 8; ++j) {
        float v = W[(size_t)(kc * 8 + j) * N + n];
        __hip_bfloat16 hb = __float2bfloat16(v);
        float vh = __bfloat162float(hb);
        __hip_bfloat16 mb = __float2bfloat16(v - vh);
        float vm = __bfloat162float(mb);
        __hip_bfloat16 lb = __float2bfloat16(v - vh - vm);
        unsigned short hh, mm2, ll;
        __builtin_memcpy(&hh, &hb, 2); __builtin_memcpy(&mm2, &mb, 2); __builtin_memcpy(&ll, &lb, 2);
        h[j] = (short)hh; m[j] = (short)mm2; l[j] = (short)ll;
    }
    const size_t PS = (size_t)N * K;
    short8* o0 = (short8*)(Wt + (size_t)n * K + kc * 8);
    short8* o1 = (short8*)(Wt + PS + (size_t)n * K + kc * 8);
    short8* o2 = (short8*)(Wt + 2 * PS + (size_t)n * K + kc * 8);
    *o0 = h; *o1 = m; *o2 = l;
}

// ---------- Plane-fused bf16 MFMA GEMM ----------
// C[z][M][N] = sum over masked (pa,pb) of A_pa[M][kslice_z] @ B_pb[N][kslice_z]^T-stored
// DBUF=0: m97 schedule (stage -> vmcnt0 -> barrier -> compute -> barrier)   [fc_in path]
// DBUF=1: 2-phase double-buffer (issue next stage, compute current, 1 barrier/step) + split-K
// XSWZ=1: bijective XCD-chunked remap: same-XCD consecutive blocks sweep the row (y) dim,
//         so each B-panel is consumed within one XCD's L2 instead of all 8.
template<int BM, int BN, int PA, int PB, unsigned PMASK, int DBUF, int XSWZ>
__global__ __launch_bounds__(256) void gemm_planes(
    const __hip_bfloat16* __restrict__ A, long aPS,
    const __hip_bfloat16* __restrict__ B, long bPS,
    int M, int N, int K, int kSlice,
    float* __restrict__ Cout)
{
    constexpr int BK = 32;
    constexpr int MT_M = BM / 32;
    constexpr int MT_N = BN / 32;
    constexpr int ASZ = PA * BM * BK;
    constexpr int BSZ = PB * BN * BK;
    constexpr int NBUF = DBUF ? 2 : 1;
    __shared__ __align__(16) __hip_bfloat16 As[NBUF * ASZ];
    __shared__ __align__(16) __hip_bfloat16 Bs[NBUF * BSZ];
    const int tid  = threadIdx.x;
    const int lane = tid & 63, wid = tid >> 6;
    const int lr = lane & 15, lg = lane >> 4;

    int bx = blockIdx.x, by = blockIdx.y, bz = blockIdx.z;
    if constexpr (XSWZ) {
        // requires gridDim.x*gridDim.y*gridDim.z % 8 == 0 (bijective; see m204 errata)
        int d    = bx + (int)gridDim.x * (by + (int)gridDim.y * bz);
        int nY   = (int)gridDim.y;
        int xcd  = d & 7;
        int rest = d >> 3;
        by = rest % nY;
        int p = (rest / nY) * 8 + xcd;        // panel id in [0, nX*nZ)
        bx = p % (int)gridDim.x;
        bz = p / (int)gridDim.x;
    }
    const int row0 = by * BM, col0 = bx * BN;
    const int wm0 = (wid >> 1) * (BM / 2), wn0 = (wid & 1) * (BN / 2);
    const int grow = lane >> 2;        // row within a 16-row staging chunk
    const int gcol = (lane & 3) * 8;   // bf16 element offset within row
    const int kBeg = bz * kSlice;
    const int kEnd = kBeg + kSlice;
    float* __restrict__ Cz = Cout + (size_t)bz * ((size_t)M * N);

    f32x4 acc[MT_M][MT_N];
    #pragma unroll
    for (int i = 0; i < MT_M; ++i)
        #pragma unroll
        for (int j = 0; j < MT_N; ++j)
            acc[i][j] = (f32x4){0.f, 0.f, 0.f, 0.f};

    constexpr int ACALLS = PA * BM / 16;   // 16 rows (1KB) per wave-call
    constexpr int BCALLS = PB * BN / 16;

    auto stageAll = [&](int kk, int bsel) {
        for (int j = wid; j < ACALLS; j += 4) {
            int pa = j / (BM / 16), sub = j % (BM / 16);
            const __hip_bfloat16* g = A + (long)pa * aPS
                + (long)(row0 + sub * 16 + grow) * K + kk + gcol;
            stage16(g, &As[bsel * ASZ + (pa * BM + sub * 16) * BK]);
        }
        for (int j = wid; j < BCALLS; j += 4) {
            int pb = j / (BN / 16), sub = j % (BN / 16);
            const __hip_bfloat16* g = B + (long)pb * bPS
                + (long)(col0 + sub * 16 + grow) * K + kk + gcol;
            stage16(g, &Bs[bsel * BSZ + (pb * BN + sub * 16) * BK]);
        }
    };

    int buf = 0;
    if constexpr (DBUF) {
        stageAll(kBeg, 0);
        asm volatile("s_waitcnt vmcnt(0)" ::: "memory");
        __syncthreads();
    }

    for (int k0 = kBeg; k0 < kEnd; k0 += BK) {
        if constexpr (DBUF) {
            if (k0 + BK < kEnd) stageAll(k0 + BK, buf ^ 1);   // issue-early, no wait
        } else {
            stageAll(k0, 0);
            asm volatile("s_waitcnt vmcnt(0)" ::: "memory");
            __syncthreads();
        }

        const __hip_bfloat16* Ab = &As[buf * ASZ];
        const __hip_bfloat16* Bb = &Bs[buf * BSZ];
        short8 af[PA][MT_M], bf[PB][MT_N];
        #pragma unroll
        for (int pa = 0; pa < PA; ++pa)
            #pragma unroll
            for (int i = 0; i < MT_M; ++i)
                af[pa][i] = *(const short8*)&Ab[(pa * BM + wm0 + i * 16 + lr) * BK + lg * 8];
        #pragma unroll
        for (int pb = 0; pb < PB; ++pb)
            #pragma unroll
            for (int j = 0; j < MT_N; ++j)
                bf[pb][j] = *(const short8*)&Bb[(pb * BN + wn0 + j * 16 + lr) * BK + lg * 8];

        #pragma unroll
        for (int pa = 0; pa < PA; ++pa)
            #pragma unroll
            for (int pb = 0; pb < PB; ++pb)
                if ((PMASK >> (pa * PB + pb)) & 1u) {
                    #pragma unroll
                    for (int i = 0; i < MT_M; ++i)
                        #pragma unroll
                        for (int j = 0; j < MT_N; ++j)
                            acc[i][j] = __builtin_amdgcn_mfma_f32_16x16x32_bf16(
                                af[pa][i], bf[pb][j], acc[i][j], 0, 0, 0);
                }
        // single barrier per k-step in DBUF mode: drain the in-flight stage of buf^1,
        // and guarantee all waves finished reading buf before it is overwritten.
        asm volatile("s_waitcnt vmcnt(0)" ::: "memory");
        __syncthreads();
        if constexpr (DBUF) buf ^= 1;
    }

    #pragma unroll
    for (int i = 0; i < MT_M; ++i) {
        #pragma unroll
        for (int j = 0; j < MT_N; ++j) {
            #pragma unroll
            for (int r = 0; r < 4; ++r) {
                int m = row0 + wm0 + i * 16 + lg * 4 + r;  // D: row=(lane>>4)*4+reg
                int n = col0 + wn0 + j * 16 + lr;          // D: col=lane&15
                Cz[(long)m * N + n] = acc[i][j][r];
            }
        }
    }
}

// ---------- Vectorized split-K reduce + bias + LIF ----------
// cur = sum_s parts[s*stride + i] + bias; mem' = beta*mem + cur - (mem>thr)*thr; spk = (mem'-thr>0)
template<int SK>
__global__ __launch_bounds__(256) void lif_vec(
    const float* __restrict__ parts, long stride4,   // stride between split planes, in float4 units
    const float* __restrict__ bias, int nMask4,      // (N/4)-1, N power of 2
    float* __restrict__ mem, __hip_bfloat16* __restrict__ spk,
    const float* __restrict__ betas, int bi,
    const float* __restrict__ thrs, int ti, int NN4)
{
    int i = blockIdx.x * 256 + threadIdx.x;
    if (i >= NN4) return;
    const float4* pb = (const float4*)parts;
    float4 cur = ((const float4*)bias)[i & nMask4];
    #pragma unroll
    for (int s = 0; s < SK; ++s) {
        float4 p = pb[(long)s * stride4 + i];
        cur.x += p.x; cur.y += p.y; cur.z += p.z; cur.w += p.w;
    }
    float beta = fminf(fmaxf(betas[bi], 0.f), 1.f);
    float thr = thrs[ti];
    float4 mo = ((const float4*)mem)[i];
    float4 mn;
    mn.x = beta * mo.x + cur.x - ((mo.x > thr) ? thr : 0.f);
    mn.y = beta * mo.y + cur.y - ((mo.y > thr) ? thr : 0.f);
    mn.z = beta * mo.z + cur.z - ((mo.z > thr) ? thr : 0.f);
    mn.w = beta * mo.w + cur.w - ((mo.w > thr) ? thr : 0.f);
    ((float4*)mem)[i] = mn;
    s16x4 sv;
    sv[0] = (mn.x - thr > 0.f) ? (short)0x3F80 : (short)0;   // bf16 1.0 / 0.0
    sv[1] = (mn.y - thr > 0.f) ? (short)0x3F80 : (short)0;
    sv[2] = (mn.z - thr > 0.f) ? (short)0x3F80 : (short)0;
    sv[3] = (mn.w - thr > 0.f) ? (short)0x3F80 : (short)0;
    ((s16x4*)spk)[i] = sv;
}

// ---------- Readout stage 1: per-(batch, chunk) partial dot, 8 chunks ----------
__global__ __launch_bounds__(256) void out_part(
    const __hip_bfloat16* __restrict__ spk2, const float* __restrict__ W_out,
    double* __restrict__ pout)
{
    const int b = blockIdx.y, chunk = blockIdx.x, tid = threadIdx.x;
    const int CH = F_OUT / 8;                       // 7168
    const __hip_bfloat16* s = spk2 + (size_t)b * F_OUT + (size_t)chunk * CH;
    const float* W = W_out + (size_t)chunk * CH * 4;
    double a0 = 0, a1 = 0, a2 = 0, a3 = 0;
    #pragma unroll
    for (int it = 0; it < 7; ++it) {
        int i = (it * 256 + tid) * 4;
        s16x4 sv = *(const s16x4*)(s + i);
        #pragma unroll
        for (int j = 0; j < 4; ++j) {
            float f = bf2f(sv[j]);
            const float4 w = *(const float4*)(W + (size_t)(i + j) * 4);
            a0 += (double)(f * w.x);
            a1 += (double)(f * w.y);
            a2 += (double)(f * w.z);
            a3 += (double)(f * w.w);
        }
    }
    __shared__ double red[256][4];
    red[tid][0] = a0; red[tid][1] = a1; red[tid][2] = a2; red[tid][3] = a3;
    __syncthreads();
    for (int s2 = 128; s2 > 0; s2 >>= 1) {
        if (tid < s2) {
            red[tid][0] += red[tid + s2][0];
            red[tid][1] += red[tid + s2][1];
            red[tid][2] += red[tid + s2][2];
            red[tid][3] += red[tid + s2][3];
        }
        __syncthreads();
    }
    if (tid < 4) pout[((size_t)b * 8 + chunk) * 4 + tid] = red[0][tid];
}

// ---------- Readout stage 2: reduce 8 chunks + output LIF ----------
__global__ __launch_bounds__(128) void out_fin(
    const double* __restrict__ pout, const float* __restrict__ b_out,
    float* __restrict__ m_out, float* __restrict__ out,
    const float* __restrict__ betas, int t)
{
    const int tid = threadIdx.x;          // 128 = 32 batches x 4 classes
    const int b = tid >> 2, c = tid & 3;
    double s = 0;
    #pragma unroll
    for (int k = 0; k < 8; ++k) s += pout[((size_t)b * 8 + k) * 4 + c];
    float beta = fminf(fmaxf(betas[3], 0.f), 1.f);
    float cur = (float)s + b_out[c];
    float mold = m_out[b * 4 + c];
    float reset = (mold > 1.0f) ? 1.0f : 0.0f;
    float mnew = beta * mold + cur - reset;
    m_out[b * 4 + c] = mnew;
    out[((size_t)t * BATCH + b) * 4 + c] = (mnew - 1.0f > 0.0f) ? 1.0f : 0.0f;
}

extern "C" void kernel_launch(void* const* d_in, const int* in_sizes, int n_in,
                              void* d_out, int out_size, void* d_ws, size_t ws_size,
                              hipStream_t stream) {
    const float* x     = (const float*)d_in[0];
    const float* W_in  = (const float*)d_in[1];
    const float* b_in  = (const float*)d_in[2];
    const float* W_h1  = (const float*)d_in[3];
    const float* b_h1  = (const float*)d_in[4];
    const float* W_h2  = (const float*)d_in[5];
    const float* b_h2  = (const float*)d_in[6];
    const float* W_out = (const float*)d_in[7];
    const float* b_out = (const float*)d_in[8];
    const float* betas = (const float*)d_in[9];
    const float* thrs  = (const float*)d_in[10];
    float* out = (float*)d_out;

    char* ws = (char*)d_ws;
    size_t off = 0;
    float* m_in  = (float*)(ws + off); off += (size_t)MROWS * H0 * 4;
    float* m_h1  = (float*)(ws + off); off += (size_t)MROWS * H1 * 4;
    float* m_h2  = (float*)(ws + off); off += (size_t)MROWS * H2 * 4;
    float* m_out = (float*)(ws + off); off += 512;
    size_t zero_bytes = off;                                   // 36,700,672
    __hip_bfloat16* WtIn = (__hip_bfloat16*)(ws + off); off += (size_t)3 * H0 * D_IN * 2;
    __hip_bfloat16* WtH1 = (__hip_bfloat16*)(ws + off); off += (size_t)3 * H1 * H0 * 2;
    __hip_bfloat16* WtH2 = (__hip_bfloat16*)(ws + off); off += (size_t)3 * H2 * H1 * 2;
    __hip_bfloat16* featP = (__hip_bfloat16*)(ws + off); off += (size_t)3 * MBIG * D_IN * 2;
    float* curAll = (float*)(ws + off); off += (size_t)MBIG * H0 * 4;
    __hip_bfloat16* spk_in = (__hip_bfloat16*)(ws + off); off += (size_t)MROWS * H0 * 2;
    __hip_bfloat16* spk1   = (__hip_bfloat16*)(ws + off); off += (size_t)MROWS * H1 * 2;
    __hip_bfloat16* spk2   = (__hip_bfloat16*)(ws + off); off += (size_t)MROWS * H2 * 2;

    // featP (88 MB) is dead after the fc_in GEMM -> reuse for split-K partials (58.7 MB)
    // and the readout partials (8 KB at +64 MiB).
    float*  parts = (float*)featP;
    double* pout  = (double*)((char*)featP + (64u << 20));

    hipMemsetAsync(d_ws, 0, zero_bytes, stream);

    wsplit<<<(H0 * (D_IN / 8) + 255) / 256, 256, 0, stream>>>(W_in, WtIn, D_IN, H0);
    wsplit<<<(H1 * (H0 / 8) + 255) / 256, 256, 0, stream>>>(W_h1, WtH1, H0, H1);
    wsplit<<<(H2 * (H1 / 8) + 255) / 256, 256, 0, stream>>>(W_h2, WtH2, H1, H2);

    pool_kernel<<<(MBIG * D_IN + 255) / 256, 256, 0, stream>>>(x, featP);

    // fc_in: 6 split products (hh,hm,mh,hl,mm,lh) fused in one K-sweep
    // 128x128 tile: doubles MFMA-per-staged-byte vs 64x128 (util bound 47%->57%)
    gemm_planes<128, 128, 3, 3, 0x5Fu, 0, 0><<<dim3(H0 / 128, MBIG / 128, 1), 256, 0, stream>>>(
        featP, (long)MBIG * D_IN, WtIn, (long)H0 * D_IN,
        MBIG, H0, D_IN, D_IN, curAll);

    const int NN1_4 = MROWS * H1 / 4;   // 917504
    const int NN2_4 = MROWS * H2 / 4;   // 458752

    for (int t = 0; t < T_STEPS; ++t) {
        // LIF0 on precomputed fc_in currents
        lif_vec<1><<<(MROWS * H0 / 4 + 255) / 256, 256, 0, stream>>>(
            curAll + (size_t)t * MROWS * H0, 0, b_in, H0 / 4 - 1,
            m_in, spk_in, betas, 0, thrs, 0, MROWS * H0 / 4);
        // h1: 256x64 tile, split-K=4, double-buffered, XCD-chunked swizzle
        gemm_planes<256, 64, 1, 3, 0x7u, 1, 1><<<dim3(H1 / 64, MROWS / 256, 4), 256, 0, stream>>>(
            spk_in, 0L, WtH1, (long)H1 * H0,
            MROWS, H1, H0, H0 / 4, parts);
        lif_vec<4><<<(NN1_4 + 255) / 256, 256, 0, stream>>>(
            parts, NN1_4, b_h1, H1 / 4 - 1,
            m_h1, spk1, betas, 1, thrs, 1, NN1_4);
        // h2: same structure
        gemm_planes<256, 64, 1, 3, 0x7u, 1, 1><<<dim3(H2 / 64, MROWS / 256, 4), 256, 0, stream>>>(
            spk1, 0L, WtH2, (long)H2 * H1,
            MROWS, H2, H1, H1 / 4, parts);
        lif_vec<4><<<(NN2_4 + 255) / 256, 256, 0, stream>>>(
            parts, NN2_4, b_h2, H2 / 4 - 1,
            m_h2, spk2, betas, 2, thrs, 2, NN2_4);
        // readout: 256-block partial stage + 1-block LIF finisher
        out_part<<<dim3(8, BATCH), 256, 0, stream>>>(spk2, W_out, pout);
        out_fin<<<1, 128, 0, stream>>>(pout, b_out, m_out, out, betas, t);
    }
    (void)in_sizes; (void)n_in; (void)out_size; (void)ws_size;
}